// Round 2
// baseline (428.852 us; speedup 1.0000x reference)
//
#include <hip/hip_runtime.h>
#include <stdint.h>

// Problem: top-k (k=50) temperature sampling over logits [256, 50257] fp32,
// must bit-match jax.random.categorical(jax.random.key(42), masked_logits).
//
// RNG: JAX >=0.4.36 defaults jax_threefry_partitionable=True. Random bits for
// flat element i are threefry2x32(key=(0,42), x=(hi32(i), lo32(i))) with the
// two 32-bit outputs XOR-folded. (Round-1 used the legacy split-iota scheme —
// wrong stream -> every sample wrong.)
//
// Strategy (one 256-thread block per row):
//   1. 4-level byte radix-select on monotone-uint32 keys of scaled = logits/T
//      -> exact fp32 value of the 50th-largest element + `need` = number of
//      threshold-equal elements kept (lowest index first, lax.top_k tie rule).
//   2. Collect candidate indices (key > T always kept; key == T kept if index
//      rank among equals < need).
//   3. For each kept candidate, compute the partitionable-threefry gumbel and
//      argmax(scaled + gumbel) with lowest-index tie-break (jnp.argmax rule).

#define VOCAB 50257
#define BATCH 256
#define NTHREADS 256
#define GT_CAP 64      // strictly-greater count is provably <= k-1 = 49
#define EQ_CAP 1024    // bit-identical fp32 collisions at threshold

__device__ __forceinline__ uint32_t rotl32(uint32_t v, int r) {
  return (v << r) | (v >> (32 - r));
}

// JAX Threefry-2x32-20 with key = (0, 42)  [jax.random.key(42)]
__device__ __forceinline__ void threefry2x32_42(uint32_t& x0, uint32_t& x1) {
  const uint32_t ks0 = 0u;
  const uint32_t ks1 = 42u;
  const uint32_t ks2 = ks0 ^ ks1 ^ 0x1BD11BDAu;
  x0 += ks0; x1 += ks1;
#define TF_R(r) { x0 += x1; x1 = rotl32(x1, (r)); x1 ^= x0; }
  TF_R(13) TF_R(15) TF_R(26) TF_R(6)
  x0 += ks1; x1 += ks2 + 1u;
  TF_R(17) TF_R(29) TF_R(16) TF_R(24)
  x0 += ks2; x1 += ks0 + 2u;
  TF_R(13) TF_R(15) TF_R(26) TF_R(6)
  x0 += ks0; x1 += ks1 + 3u;
  TF_R(17) TF_R(29) TF_R(16) TF_R(24)
  x0 += ks1; x1 += ks2 + 4u;
  TF_R(13) TF_R(15) TF_R(26) TF_R(6)
  x0 += ks2; x1 += ks0 + 5u;
#undef TF_R
}

// Gumbel noise at flat index i of the [256,50257] float32 array, replicating
// jax.random.gumbel(key(42), ...) under jax_threefry_partitionable=True:
//   counter = uint64 flat index; x0 = hi32 (=0 here), x1 = lo32; bits = o0^o1.
__device__ __forceinline__ float gumbel_at(uint32_t flat) {
  uint32_t x0 = 0u;        // hi32 of 64-bit counter (size < 2^32)
  uint32_t x1 = flat;      // lo32
  threefry2x32_42(x0, x1);
  uint32_t bits = x0 ^ x1; // partitionable path XOR-folds the pair
  // uniform in [tiny, 1): mantissa-fill trick; ref's floats*(1-tiny)+tiny then
  // max(tiny, .) reduces bit-exactly to (floats==0 ? tiny : floats).
  uint32_t fb = (bits >> 9) | 0x3f800000u;
  float f = __uint_as_float(fb) - 1.0f;              // exact
  float u = fmaxf(f, 1.17549435e-38f);
  // -log(-log(u)) with fp32 intermediate rounding like the reference,
  // each log computed in double (correctly-rounded fp32 result).
  float t = (float)log((double)u);                   // t < 0
  float g = (float)(-log((double)(-t)));
  return g;
}

// Monotone float->uint32 key: larger float => larger key (no NaNs in data).
__device__ __forceinline__ uint32_t fkey(float x) {
  uint32_t u = __float_as_uint(x);
  return (u & 0x80000000u) ? ~u : (u | 0x80000000u);
}

extern "C" __global__ void __launch_bounds__(NTHREADS)
topk_sample_kernel(const float* __restrict__ logits,
                   const float* __restrict__ temp_p,
                   const int* __restrict__ topk_p,
                   int* __restrict__ out) {
  const int row = blockIdx.x;
  const int tid = threadIdx.x;
  const float temp = temp_p[0];
  const int K = topk_p[0];
  const float* rowp = logits + (size_t)row * VOCAB;

  __shared__ unsigned int hist[256];
  __shared__ uint32_t sh_prefix;
  __shared__ int sh_need;
  __shared__ int s_gidx[GT_CAP];
  __shared__ int s_eidx[EQ_CAP];
  __shared__ int s_gcnt, s_ecnt;
  __shared__ float red_v[NTHREADS];
  __shared__ int red_i[NTHREADS];

  // ---- 4-level byte radix select (MSB -> LSB) for the K-th largest key ----
  const uint32_t highmask_tab[4] = {0u, 0xFF000000u, 0xFFFF0000u, 0xFFFFFF00u};
  uint32_t prefix = 0;
  int need = K;
  for (int level = 0; level < 4; ++level) {
    const int shift = 24 - level * 8;
    const uint32_t hm = highmask_tab[level];
    hist[tid] = 0u;
    __syncthreads();
    for (int i = tid; i < VOCAB; i += NTHREADS) {
      float s = rowp[i] / temp;                       // IEEE fp32 div, matches ref
      uint32_t key = fkey(s);
      if (((key ^ prefix) & hm) == 0u) {
        atomicAdd(&hist[(key >> shift) & 0xFFu], 1u);
      }
    }
    __syncthreads();
    if (tid == 0) {
      unsigned int cum = 0;
      int b = 255;
      for (; b > 0; --b) {
        unsigned int c = hist[b];
        if (cum + c >= (unsigned int)need) break;
        cum += c;
      }
      sh_prefix = prefix | ((uint32_t)b << shift);
      sh_need = need - (int)cum;                      // stays >= 1
    }
    __syncthreads();
    prefix = sh_prefix;
    need = sh_need;
    __syncthreads();
  }
  const uint32_t T = prefix;   // exact transformed key of the K-th largest value

  // ---- collect candidates ----
  if (tid == 0) { s_gcnt = 0; s_ecnt = 0; }
  __syncthreads();
  for (int i = tid; i < VOCAB; i += NTHREADS) {
    float s = rowp[i] / temp;
    uint32_t key = fkey(s);
    if (key > T) {
      int p = atomicAdd(&s_gcnt, 1);
      if (p < GT_CAP) s_gidx[p] = i;
    } else if (key == T) {
      int p = atomicAdd(&s_ecnt, 1);
      if (p < EQ_CAP) s_eidx[p] = i;
    }
  }
  __syncthreads();

  const int gcnt = s_gcnt;                 // == K - need, <= 49
  const int ecnt = min(s_ecnt, EQ_CAP);

  float bestv = -__builtin_huge_valf();
  int besti = 0x7fffffff;

  // strictly-greater candidates: all kept
  for (int c = tid; c < gcnt; c += NTHREADS) {
    int idx = s_gidx[c];
    float v = rowp[idx] / temp + gumbel_at((uint32_t)row * (uint32_t)VOCAB + (uint32_t)idx);
    if (v > bestv || (v == bestv && idx < besti)) { bestv = v; besti = idx; }
  }
  // threshold-equal candidates: keep the `need` lowest indices (lax.top_k tie rule)
  for (int e = tid; e < ecnt; e += NTHREADS) {
    int idx = s_eidx[e];
    int rank = 0;
    for (int j = 0; j < ecnt; ++j) rank += (s_eidx[j] < idx) ? 1 : 0;
    if (rank < need) {
      float v = rowp[idx] / temp + gumbel_at((uint32_t)row * (uint32_t)VOCAB + (uint32_t)idx);
      if (v > bestv || (v == bestv && idx < besti)) { bestv = v; besti = idx; }
    }
  }

  // ---- block argmax reduction, lowest-index tie-break ----
  red_v[tid] = bestv;
  red_i[tid] = besti;
  __syncthreads();
  for (int off = NTHREADS / 2; off > 0; off >>= 1) {
    if (tid < off) {
      float v2 = red_v[tid + off];
      int i2 = red_i[tid + off];
      if (v2 > red_v[tid] || (v2 == red_v[tid] && i2 < red_i[tid])) {
        red_v[tid] = v2;
        red_i[tid] = i2;
      }
    }
    __syncthreads();
  }
  if (tid == 0) out[row] = red_i[0];
}

extern "C" void kernel_launch(void* const* d_in, const int* in_sizes, int n_in,
                              void* d_out, int out_size, void* d_ws, size_t ws_size,
                              hipStream_t stream) {
  const float* logits = (const float*)d_in[0];
  const float* temp_p = (const float*)d_in[1];
  const int* topk_p = (const int*)d_in[2];
  int* out = (int*)d_out;
  hipLaunchKernelGGL(topk_sample_kernel, dim3(BATCH), dim3(NTHREADS), 0, stream,
                     logits, temp_p, topk_p, out);
}

// Round 3
// 103.251 us; speedup vs baseline: 4.1535x; 4.1535x over previous
//
#include <hip/hip_runtime.h>
#include <stdint.h>

// Top-k (k=50) temperature sampling, bit-matching
// jax.random.categorical(key(42), topk_mask(logits/T, 50)) with
// jax_threefry_partitionable=True (verified passing in round 2).
//
// Round-3 structure (one 1024-thread block per row, 2 data scans):
//   Scan 1: 4096-bin histogram of the top-12 bits of the monotone key of the
//           RAW logit (division is monotone => same ordering; no divides in
//           the hot loop). Elements below key(4.0) skip the atomic (top-50
//           sits at ~3.1 sigma = ~12.4; exact fallback rescan if < k survive).
//           Parallel suffix-scan over bins -> threshold bin tb.
//   Scan 2: collect indices of all elements with bin >= tb-1 (one full spare
//           bin guarantees every s-space tie group is fully contained:
//           division collapses at most a few ulps; a bin spans 1/8 octave).
//   Refine: exact IEEE s = l/temp for the ~200 candidates, exact
//           (s_key, index) rank -> keep rank < k (lax.top_k tie rule),
//           gumbel via partitionable threefry, argmax with lowest-index
//           tie-break (jnp.argmax rule).

#define VOCAB 50257
#define BATCH 256
#define NT 1024
#define NBINS 4096
#define CAND_CAP 2048
#define FILTER_VAL 4.0f

__device__ __forceinline__ uint32_t rotl32(uint32_t v, int r) {
  return (v << r) | (v >> (32 - r));
}

// JAX Threefry-2x32-20, key = (0, 42)
__device__ __forceinline__ void threefry2x32_42(uint32_t& x0, uint32_t& x1) {
  const uint32_t ks0 = 0u;
  const uint32_t ks1 = 42u;
  const uint32_t ks2 = ks0 ^ ks1 ^ 0x1BD11BDAu;
  x0 += ks0; x1 += ks1;
#define TF_R(r) { x0 += x1; x1 = rotl32(x1, (r)); x1 ^= x0; }
  TF_R(13) TF_R(15) TF_R(26) TF_R(6)
  x0 += ks1; x1 += ks2 + 1u;
  TF_R(17) TF_R(29) TF_R(16) TF_R(24)
  x0 += ks2; x1 += ks0 + 2u;
  TF_R(13) TF_R(15) TF_R(26) TF_R(6)
  x0 += ks0; x1 += ks1 + 3u;
  TF_R(17) TF_R(29) TF_R(16) TF_R(24)
  x0 += ks1; x1 += ks2 + 4u;
  TF_R(13) TF_R(15) TF_R(26) TF_R(6)
  x0 += ks2; x1 += ks0 + 5u;
#undef TF_R
}

// Gumbel noise at flat index i, jax_threefry_partitionable=True:
// counter = u64 flat index -> (hi32=0, lo32=i), bits = out0 ^ out1.
__device__ __forceinline__ float gumbel_at(uint32_t flat) {
  uint32_t x0 = 0u, x1 = flat;
  threefry2x32_42(x0, x1);
  uint32_t bits = x0 ^ x1;
  uint32_t fb = (bits >> 9) | 0x3f800000u;
  float f = __uint_as_float(fb) - 1.0f;          // exact
  float u = fmaxf(f, 1.17549435e-38f);
  float t = (float)log((double)u);               // correctly-rounded fp32 path
  float g = (float)(-log((double)(-t)));
  return g;
}

// Monotone float->uint32 key (no NaNs in data).
__device__ __forceinline__ uint32_t fkey(float x) {
  uint32_t u = __float_as_uint(x);
  return (u & 0x80000000u) ? ~u : (u | 0x80000000u);
}

extern "C" __global__ void __launch_bounds__(NT)
topk_sample_kernel(const float* __restrict__ logits,
                   const float* __restrict__ temp_p,
                   const int* __restrict__ topk_p,
                   int* __restrict__ out) {
  const int row = blockIdx.x;
  const int tid = threadIdx.x;
  const float temp = temp_p[0];
  const int K = topk_p[0];
  const float* rowp = logits + (size_t)row * VOCAB;

  // rows are only 4B-aligned (VOCAB*4 % 16 == 4): scalar prologue to 16B.
  const int pc = (4 - (row & 3)) & 3;
  const int nv4 = (VOCAB - pc) >> 2;
  const int tailbase = pc + (nv4 << 2);
  const int tailc = VOCAB - tailbase;        // 0..3
  const float4* body = (const float4*)(rowp + pc);

  __shared__ unsigned hist[NBINS];
  __shared__ unsigned wtot[16];
  __shared__ unsigned aboveWave[16];
  __shared__ int sh_tb, sh_total, sh_cnt;
  __shared__ unsigned ckey[CAND_CAP];
  __shared__ int cidx[CAND_CAP];
  __shared__ float red_v[NT];
  __shared__ int red_i[NT];

  const int lane = tid & 63;
  const int wave = tid >> 6;

  // ---- Scan 1: filtered histogram + threshold bin ----
  uint32_t filt = fkey(FILTER_VAL);
  int tb = 0;
  for (;;) {
    for (int b = tid; b < NBINS; b += NT) hist[b] = 0u;
    __syncthreads();
    if (tid < pc) {
      uint32_t k = fkey(rowp[tid]);
      if (k >= filt) atomicAdd(&hist[k >> 20], 1u);
    }
    for (int v = tid; v < nv4; v += NT) {
      float4 x = body[v];
      uint32_t k0 = fkey(x.x), k1 = fkey(x.y), k2 = fkey(x.z), k3 = fkey(x.w);
      if (k0 >= filt) atomicAdd(&hist[k0 >> 20], 1u);
      if (k1 >= filt) atomicAdd(&hist[k1 >> 20], 1u);
      if (k2 >= filt) atomicAdd(&hist[k2 >> 20], 1u);
      if (k3 >= filt) atomicAdd(&hist[k3 >> 20], 1u);
    }
    if (tid < tailc) {
      uint32_t k = fkey(rowp[tailbase + tid]);
      if (k >= filt) atomicAdd(&hist[k >> 20], 1u);
    }
    __syncthreads();

    // parallel suffix-scan: thread t owns bins [4t, 4t+3] (ascending key order)
    unsigned p = hist[4 * tid] + hist[4 * tid + 1] + hist[4 * tid + 2] + hist[4 * tid + 3];
    unsigned v = p;
    for (int off = 1; off < 64; off <<= 1) {
      unsigned o = (unsigned)__shfl_down((int)v, off);
      if (lane + off < 64) v += o;     // inclusive suffix sum within wave
    }
    if (lane == 0) wtot[wave] = v;
    __syncthreads();
    if (tid == 0) {
      unsigned acc = 0;
      for (int w = 15; w >= 0; --w) { aboveWave[w] = acc; acc += wtot[w]; }
      sh_total = (int)acc;
    }
    __syncthreads();
    unsigned above = aboveWave[wave] + (v - p);   // count in bins strictly above chunk
    if (above < (unsigned)K && above + p >= (unsigned)K) {  // unique crossing thread
      int need = K - (int)above;
      for (int b = 3; b >= 0; --b) {
        unsigned c = hist[4 * tid + b];
        if (c >= (unsigned)need) { sh_tb = 4 * tid + b; break; }
        need -= (int)c;
      }
    }
    __syncthreads();
    if (sh_total >= K) { tb = sh_tb; break; }
    filt = 0u;                         // exact fallback (never taken: ~8000 >= 4.0)
    __syncthreads();
  }

  // ---- Scan 2: collect candidates with bin >= tb-1 ----
  const uint32_t cutk = (uint32_t)max(tb - 1, 0) << 20;
  if (tid == 0) sh_cnt = 0;
  __syncthreads();
  if (tid < pc) {
    if (fkey(rowp[tid]) >= cutk) {
      int p = atomicAdd(&sh_cnt, 1);
      if (p < CAND_CAP) cidx[p] = tid;
    }
  }
  for (int v = tid; v < nv4; v += NT) {
    float4 x = body[v];
    int base = pc + (v << 2);
    if (fkey(x.x) >= cutk) { int p = atomicAdd(&sh_cnt, 1); if (p < CAND_CAP) cidx[p] = base; }
    if (fkey(x.y) >= cutk) { int p = atomicAdd(&sh_cnt, 1); if (p < CAND_CAP) cidx[p] = base + 1; }
    if (fkey(x.z) >= cutk) { int p = atomicAdd(&sh_cnt, 1); if (p < CAND_CAP) cidx[p] = base + 2; }
    if (fkey(x.w) >= cutk) { int p = atomicAdd(&sh_cnt, 1); if (p < CAND_CAP) cidx[p] = base + 3; }
  }
  if (tid < tailc) {
    if (fkey(rowp[tailbase + tid]) >= cutk) {
      int p = atomicAdd(&sh_cnt, 1);
      if (p < CAND_CAP) cidx[p] = tailbase + tid;
    }
  }
  __syncthreads();
  const int C = min(sh_cnt, CAND_CAP);

  // ---- Refine: exact s-keys, exact rank, gumbel, argmax ----
  if (tid < C) {
    int idx = cidx[tid];
    float s = rowp[idx] / temp;        // IEEE fp32 div, matches reference
    ckey[tid] = fkey(s);
  }
  __syncthreads();

  float bestv = -__builtin_huge_valf();
  int besti = 0x7fffffff;
  if (tid < C) {
    const uint32_t mk = ckey[tid];
    const int mi = cidx[tid];
    int rank = 0;
    for (int j = 0; j < C; ++j) {
      uint32_t k = ckey[j];
      rank += (k > mk || (k == mk && cidx[j] < mi)) ? 1 : 0;
    }
    if (rank < K) {                    // exact lax.top_k membership (low-index ties)
      float s = rowp[mi] / temp;
      float v = s + gumbel_at((uint32_t)row * (uint32_t)VOCAB + (uint32_t)mi);
      bestv = v; besti = mi;
    }
  }

  red_v[tid] = bestv;
  red_i[tid] = besti;
  __syncthreads();
  for (int off = NT / 2; off > 0; off >>= 1) {
    if (tid < off) {
      float v2 = red_v[tid + off];
      int i2 = red_i[tid + off];
      if (v2 > red_v[tid] || (v2 == red_v[tid] && i2 < red_i[tid])) {
        red_v[tid] = v2;
        red_i[tid] = i2;
      }
    }
    __syncthreads();
  }
  if (tid == 0) out[row] = red_i[0];
}

extern "C" void kernel_launch(void* const* d_in, const int* in_sizes, int n_in,
                              void* d_out, int out_size, void* d_ws, size_t ws_size,
                              hipStream_t stream) {
  const float* logits = (const float*)d_in[0];
  const float* temp_p = (const float*)d_in[1];
  const int* topk_p = (const int*)d_in[2];
  int* out = (int*)d_out;
  hipLaunchKernelGGL(topk_sample_kernel, dim3(BATCH), dim3(NT), 0, stream,
                     logits, temp_p, topk_p, out);
}